// Round 9
// baseline (463.556 us; speedup 1.0000x reference)
//
#include <hip/hip_runtime.h>
#include <stdint.h>

#define B_  2
#define T_  2048
#define C_  2048
#define NH  16
#define HD  128
#define M_  (B_*T_)   // 4096

typedef unsigned short ushort_t;
typedef unsigned int uint;
typedef __attribute__((ext_vector_type(8))) short short8;
typedef __attribute__((ext_vector_type(4))) float f32x4;
typedef __attribute__((ext_vector_type(16))) float f32x16;

#if __has_builtin(__builtin_amdgcn_exp2f)
#define EXP2 __builtin_amdgcn_exp2f
#else
#define EXP2 exp2f
#endif

__device__ inline ushort_t f2b(float f) {
  union { float f; unsigned u; } x; x.f = f;
  unsigned r = (x.u + 0x7fffu + ((x.u >> 16) & 1u)) >> 16;
  return (ushort_t)r;
}
__device__ inline float b2f(ushort_t b) {
  union { unsigned u; float f; } x; x.u = ((unsigned)b) << 16;
  return x.f;
}
__device__ inline uint cvtpk(float lo, float hi) {
  uint d;
  asm("v_cvt_pk_bf16_f32 %0, %1, %2" : "=v"(d) : "v"(lo), "v"(hi));
  return d;
}
__device__ inline void pl32swap(uint& a, uint& b) {
  asm volatile("v_permlane32_swap_b32 %0, %1" : "+v"(a), "+v"(b));
}
__device__ inline void gload_lds16(const void* g, void* l) {
  __builtin_amdgcn_global_load_lds((const __attribute__((address_space(1))) void*)g,
                                   (__attribute__((address_space(3))) void*)l, 16, 0, 0);
}

// ---------------- x fp32 -> bf16 ----------------
__global__ __launch_bounds__(256) void cvt_f32_bf16(const float* __restrict__ in,
                                                    ushort_t* __restrict__ out, int n4) {
  int i = blockIdx.x * 256 + threadIdx.x;
  if (i >= n4) return;
  float4 v = ((const float4*)in)[i];
  unsigned long long pk = (unsigned long long)f2b(v.x)
                        | ((unsigned long long)f2b(v.y) << 16)
                        | ((unsigned long long)f2b(v.z) << 32)
                        | ((unsigned long long)f2b(v.w) << 48);
  ((unsigned long long*)out)[i] = pk;
}

// ---------------- transpose (+convert) to bf16, out[(col)*rows + row], vector IO ----------------
template<int FROM_F32>
__global__ __launch_bounds__(256) void transpose_to_bf16(const void* __restrict__ inv,
                                                         ushort_t* __restrict__ out,
                                                         int rows, int cols) {
  __shared__ __align__(16) ushort_t tile[64][72];
  const int t = threadIdx.x;
  const int br = blockIdx.y * 64, bc = blockIdx.x * 64;
  if (FROM_F32) {
    const float* in = (const float*)inv;
    const int vc = t & 15, r0 = t >> 4;   // 4-col groups
#pragma unroll
    for (int i = 0; i < 4; i++) {
      int row = r0 + 16 * i;
      float4 v = *(const float4*)&in[(size_t)(br + row) * cols + bc + vc * 4];
      tile[row][vc * 4 + 0] = f2b(v.x);
      tile[row][vc * 4 + 1] = f2b(v.y);
      tile[row][vc * 4 + 2] = f2b(v.z);
      tile[row][vc * 4 + 3] = f2b(v.w);
    }
  } else {
    const ushort_t* in = (const ushort_t*)inv;
    const int vc = t & 7, r0 = t >> 3;    // 8-col groups
#pragma unroll
    for (int i = 0; i < 2; i++) {
      int row = r0 + 32 * i;
      short8 v = *(const short8*)&in[(size_t)(br + row) * cols + bc + vc * 8];
#pragma unroll
      for (int j = 0; j < 8; j++) tile[row][vc * 8 + j] = (ushort_t)v[j];
    }
  }
  __syncthreads();
  const int oc = t >> 2;                   // output row = orig col, 0..63
#pragma unroll
  for (int s2 = 0; s2 < 2; s2++) {
    int seg = (t & 3) + 4 * s2;            // 8-orig-row group
    short8 w;
#pragma unroll
    for (int j = 0; j < 8; j++) w[j] = (short)tile[seg * 8 + j][oc];
    *(short8*)&out[(size_t)(bc + oc) * rows + br + seg * 8] = w;
  }
}

// ---------------- RoPE cos/sin table: [T_][64] ----------------
__global__ __launch_bounds__(256) void rope_table(float* __restrict__ cs, float* __restrict__ sn) {
  int i = blockIdx.x * 256 + threadIdx.x;   // T_*64
  int tt = i >> 6, f = i & 63;
  float inv = powf(10000.0f, -(float)(2 * f) / 128.0f);
  float ang = (float)tt * inv;
  cs[i] = cosf(ang);
  sn[i] = sinf(ang);
}

// ---------------- RoPE apply in place on Q and K (bf16), vectorized ----------------
__global__ __launch_bounds__(256) void rope_apply(ushort_t* __restrict__ Q, ushort_t* __restrict__ K,
                                                  const float* __restrict__ cs,
                                                  const float* __restrict__ sn) {
  int i = blockIdx.x * 256 + threadIdx.x;   // M_*C_/8 groups of 8 elems (4 pairs)
  int row = i >> 8, g = i & 255;
  int tt = row & (T_ - 1);
  int fb = (g * 4) & 63;
  f32x4 cv = *(const f32x4*)&cs[(tt << 6) + fb];
  f32x4 sv = *(const f32x4*)&sn[(tt << 6) + fb];
  size_t idx = ((size_t)row << 11) + (size_t)g * 8;
  short8 q = *(const short8*)&Q[idx];
  short8 k = *(const short8*)&K[idx];
#pragma unroll
  for (int j = 0; j < 4; j++) {
    float c = cv[j], s = sv[j];
    float qr = b2f((ushort_t)q[2 * j]), qi = b2f((ushort_t)q[2 * j + 1]);
    q[2 * j]     = (short)f2b(qr * c - qi * s);
    q[2 * j + 1] = (short)f2b(qr * s + qi * c);
    float kr = b2f((ushort_t)k[2 * j]), ki = b2f((ushort_t)k[2 * j + 1]);
    k[2 * j]     = (short)f2b(kr * c - ki * s);
    k[2 * j + 1] = (short)f2b(kr * s + ki * c);
  }
  *(short8*)&Q[idx] = q;
  *(short8*)&K[idx] = k;
}

// ---------------- GEMM v3: BM=256 x BN=128, BK=64, 8 waves (4Mx2N), 3-deep LDS pipeline ----------------
template<int OUTF32>
__global__ __launch_bounds__(512, 2) void gemm_bt3(const ushort_t* __restrict__ A,
                                                   const ushort_t* __restrict__ Bt0,
                                                   const ushort_t* __restrict__ Bt1,
                                                   const ushort_t* __restrict__ Bt2,
                                                   void* __restrict__ O0, void* __restrict__ O1,
                                                   void* __restrict__ O2, int N, int K) {
  extern __shared__ __align__(16) ushort_t lds[];   // 3 * 24576 elems = 144 KiB
  const int z = blockIdx.z;
  const ushort_t* Bt = (z == 0) ? Bt0 : (z == 1) ? Bt1 : Bt2;
  void* Ov = (z == 0) ? O0 : (z == 1) ? O1 : O2;
  const int tid = threadIdx.x;
  const int lane = tid & 63, wave = tid >> 6;
  const int lr = lane & 15, lg = lane >> 4;
  const int wm = wave >> 1, wn = wave & 1;          // 4 M-waves x 2 N-waves
  const int swz = lr & 7;
  const int bm = blockIdx.y, bn = blockIdx.x;
  const ushort_t* Ap = A + (size_t)bm * 256 * K;
  const ushort_t* Bp = Bt + (size_t)bn * 128 * K;
  const int NT = K >> 6;

  f32x4 acc[4][4] = {};

  auto stage = [&](int k0, int buf) {
    const int base = buf * 24576;
#pragma unroll
    for (int i = 0; i < 4; i++) {
      int idx = i * 512 + tid;
      int row = idx >> 3;
      int c = (idx & 7) ^ (row & 7);                 // inverse-swizzled source chunk
      gload_lds16(Ap + (size_t)row * K + k0 + c * 8, &lds[(size_t)(base + idx * 8)]);
    }
#pragma unroll
    for (int i = 0; i < 2; i++) {
      int idx = i * 512 + tid;
      int row = idx >> 3;
      int c = (idx & 7) ^ (row & 7);
      gload_lds16(Bp + (size_t)row * K + k0 + c * 8, &lds[(size_t)(base + 16384 + idx * 8)]);
    }
  };

  stage(0, 0);
  stage(64, 1);

  for (int t = 0; t < NT; t++) {
    if (t + 2 < NT) stage((t + 2) << 6, (t + 2) % 3);
    if (t < NT - 2)       asm volatile("s_waitcnt vmcnt(12)" ::: "memory");
    else if (t == NT - 2) asm volatile("s_waitcnt vmcnt(6)"  ::: "memory");
    else                  asm volatile("s_waitcnt vmcnt(0)"  ::: "memory");
    __builtin_amdgcn_s_barrier();                    // tile t visible to all waves
    const int abase = (t % 3) * 24576, bbase = abase + 16384;
    __builtin_amdgcn_s_setprio(1);
#pragma unroll
    for (int kk = 0; kk < 2; kk++) {
      short8 af[4], bf[4];
      const int ch = ((kk * 4 + lg) ^ swz) * 8;
#pragma unroll
      for (int mf = 0; mf < 4; mf++)
        af[mf] = *(const short8*)&lds[abase + (wm * 64 + mf * 16 + lr) * 64 + ch];
#pragma unroll
      for (int nf = 0; nf < 4; nf++)
        bf[nf] = *(const short8*)&lds[bbase + (wn * 64 + nf * 16 + lr) * 64 + ch];
#pragma unroll
      for (int mf = 0; mf < 4; mf++)
#pragma unroll
        for (int nf = 0; nf < 4; nf++)
          acc[mf][nf] = __builtin_amdgcn_mfma_f32_16x16x32_bf16(af[mf], bf[nf], acc[mf][nf], 0, 0, 0);
    }
    __builtin_amdgcn_s_setprio(0);
    __builtin_amdgcn_s_barrier();                    // close reads of buf t%3
  }

  const int row0 = bm * 256 + wm * 64 + lg * 4;
  const int col0 = bn * 128 + wn * 64 + lr;
  if (OUTF32) {
    float* O = (float*)Ov;
#pragma unroll
    for (int mf = 0; mf < 4; mf++)
#pragma unroll
      for (int nf = 0; nf < 4; nf++)
#pragma unroll
        for (int r = 0; r < 4; r++)
          O[(size_t)(row0 + mf * 16 + r) * N + col0 + nf * 16] = acc[mf][nf][r];
  } else {
    ushort_t* O = (ushort_t*)Ov;
#pragma unroll
    for (int mf = 0; mf < 4; mf++)
#pragma unroll
      for (int nf = 0; nf < 4; nf++)
#pragma unroll
        for (int r = 0; r < 4; r++)
          O[(size_t)(row0 + mf * 16 + r) * N + col0 + nf * 16] = f2b(acc[mf][nf][r]);
  }
}

// ---------------- Flash attention v4: swapped-QK 32x32, 2-wave KV split + exact merge ----------------
// 1024 blocks x 128 threads (2 waves) -> 8 waves/CU = 2/SIMD (latency hiding; was 1/SIMD).
// Block handles q-tile pair {widx, 63-widx}. Wave w does KV steps k0 = w*32, w*32+64, ...
// (strided split, balanced +-1); each keeps partial (m, l, O). Exact f32 merge via LDS:
// M=max(m0,m1); O = sum o_w*2^(m_w-M); L = sum l_w*2^(m_w-M); wave w' writes d-blocks {2w',2w'+1}.
// QK^T chain split into two 4-deep MFMA chains (sa+sb) to halve intra-wave latency.
__global__ __launch_bounds__(128) void flash_attn4(const ushort_t* __restrict__ Q,
                                                   const ushort_t* __restrict__ K,
                                                   const ushort_t* __restrict__ Vt,
                                                   ushort_t* __restrict__ AO) {
  __shared__ float oLds[2][64][64];     // [wave][reg 0..63][lane] f32 = 32 KiB
  __shared__ float mlLds[2][2][32];     // [wave][m/l][qcol]
  // XCD swizzle: 1024 blocks -> 128 consecutive per XCD (4 bh's K/V colocate in L2)
  int flat = blockIdx.x;
  int swz = (flat & 7) * 128 + (flat >> 3);
  const int bh = swz >> 5, widx = swz & 31;
  const int b = bh >> 4, h = bh & 15;
  const int w = threadIdx.x >> 6;       // 0..1
  const int lane = threadIdx.x & 63;
  const int col = lane & 31, hi = lane >> 5, hioff = 4 * hi;
  const ushort_t* Qb = Q + (size_t)b * T_ * C_ + (size_t)h * HD;
  const ushort_t* Kb = K + (size_t)b * T_ * C_ + (size_t)h * HD;
  const ushort_t* Vb = Vt + (size_t)bh * (size_t)HD * T_;
  const float sc = 0.12754245f;  // log2(e)/sqrt(128)

#pragma unroll 1
  for (int ph = 0; ph < 2; ph++) {
    const int tile = ph ? (63 - widx) : widx;
    const int q0 = tile * 32;
    const int qcol = q0 + col;
    // Q B-fragments: lane holds Q[q0+col][db*16 + hi*8 + e]
    short8 qf[8];
#pragma unroll
    for (int db = 0; db < 8; db++)
      qf[db] = *(const short8*)&Qb[(size_t)qcol * C_ + db * 16 + hi * 8];

    f32x16 o0 = {}, o1 = {}, o2 = {}, o3 = {};
    float m = -1e30f, l = 0.f;
    const int kstart = w * 32;

    if (kstart <= q0) {
      short8 kf[8];
#pragma unroll
      for (int db = 0; db < 8; db++)
        kf[db] = *(const short8*)&Kb[(size_t)(kstart + col) * C_ + db * 16 + hi * 8];

#pragma unroll 1
      for (int k0 = kstart; k0 <= q0; k0 += 64) {
        // S^T[k][q] over d=128, two independent 4-deep chains
        f32x16 sa = {}, sb = {};
#pragma unroll
        for (int db = 0; db < 4; db++) {
          sa = __builtin_amdgcn_mfma_f32_32x32x16_bf16(kf[db],     qf[db],     sa, 0, 0, 0);
          sb = __builtin_amdgcn_mfma_f32_32x32x16_bf16(kf[db + 4], qf[db + 4], sb, 0, 0, 0);
        }
        // prefetch next K tile (this wave's next step)
        if (k0 + 64 <= q0) {
#pragma unroll
          for (int db = 0; db < 8; db++)
            kf[db] = *(const short8*)&Kb[(size_t)(k0 + 64 + col) * C_ + db * 16 + hi * 8];
        }
        // V loads early (used after softmax)
        short8 va[4][2];
#pragma unroll
        for (int dblk = 0; dblk < 4; dblk++)
#pragma unroll
          for (int j = 0; j < 2; j++)
            va[dblk][j] = *(const short8*)&Vb[(size_t)(dblk * 32 + col) * T_ + k0 + j * 16 + hi * 8];

        // scale + causal mask. k-row of reg r: k0 + (r&3)+8*(r>>2)+4*hi
        f32x16 s;
        const bool domask = (k0 + 31 > q0);
        if (domask) {
#pragma unroll
          for (int r = 0; r < 16; r++) {
            int krow = k0 + ((r & 3) + 8 * (r >> 2)) + hioff;
            float v = (sa[r] + sb[r]) * sc;
            s[r] = (krow > qcol) ? -1e30f : v;
          }
        } else {
#pragma unroll
          for (int r = 0; r < 16; r++) s[r] = (sa[r] + sb[r]) * sc;
        }
        // row max: 15 in-register + 1 xor32
        float tm = s[0];
#pragma unroll
        for (int r = 1; r < 16; r++) tm = fmaxf(tm, s[r]);
        tm = fmaxf(tm, __shfl_xor(tm, 32, 64));
        // online-softmax with defer-max (T13)
        if (!__all(tm <= m + 8.0f)) {
          float mn = fmaxf(m, tm);
          float corr = EXP2(m - mn);
          m = mn;
          l *= corr;
#pragma unroll
          for (int r = 0; r < 16; r++) { o0[r] *= corr; o1[r] *= corr; o2[r] *= corr; o3[r] *= corr; }
        }
#pragma unroll
        for (int r = 0; r < 16; r++) s[r] = EXP2(s[r] - m);
        float rs = s[0];
#pragma unroll
        for (int r = 1; r < 16; r++) rs += s[r];
        rs += __shfl_xor(rs, 32, 64);
        l += rs;
        // P^T B-frags via cvt_pk + permlane32_swap (T12 derivation)
        uint c0 = cvtpk(s[0], s[1]),  c1 = cvtpk(s[2], s[3]);
        uint c2 = cvtpk(s[4], s[5]),  c3 = cvtpk(s[6], s[7]);
        uint c4 = cvtpk(s[8], s[9]),  c5 = cvtpk(s[10], s[11]);
        uint c6 = cvtpk(s[12], s[13]), c7 = cvtpk(s[14], s[15]);
        pl32swap(c0, c2); pl32swap(c1, c3);
        pl32swap(c4, c6); pl32swap(c5, c7);
        union { uint u[4]; short8 v; } pb0, pb1;
        pb0.u[0] = c0; pb0.u[1] = c1; pb0.u[2] = c2; pb0.u[3] = c3;
        pb1.u[0] = c4; pb1.u[1] = c5; pb1.u[2] = c6; pb1.u[3] = c7;
        // PV: O^T[d][q] += V^T[d][k] P^T[k][q]
        o0 = __builtin_amdgcn_mfma_f32_32x32x16_bf16(va[0][0], pb0.v, o0, 0, 0, 0);
        o1 = __builtin_amdgcn_mfma_f32_32x32x16_bf16(va[1][0], pb0.v, o1, 0, 0, 0);
        o2 = __builtin_amdgcn_mfma_f32_32x32x16_bf16(va[2][0], pb0.v, o2, 0, 0, 0);
        o3 = __builtin_amdgcn_mfma_f32_32x32x16_bf16(va[3][0], pb0.v, o3, 0, 0, 0);
        o0 = __builtin_amdgcn_mfma_f32_32x32x16_bf16(va[0][1], pb1.v, o0, 0, 0, 0);
        o1 = __builtin_amdgcn_mfma_f32_32x32x16_bf16(va[1][1], pb1.v, o1, 0, 0, 0);
        o2 = __builtin_amdgcn_mfma_f32_32x32x16_bf16(va[2][1], pb1.v, o2, 0, 0, 0);
        o3 = __builtin_amdgcn_mfma_f32_32x32x16_bf16(va[3][1], pb1.v, o3, 0, 0, 0);
      }
    }
    // ---- store partials ----
#pragma unroll
    for (int r = 0; r < 16; r++) {
      oLds[w][r][lane]      = o0[r];
      oLds[w][16 + r][lane] = o1[r];
      oLds[w][32 + r][lane] = o2[r];
      oLds[w][48 + r][lane] = o3[r];
    }
    if (lane < 32) { mlLds[w][0][lane] = m; mlLds[w][1][lane] = l; }
    __syncthreads();
    // ---- exact merge; wave w writes d-blocks {2w, 2w+1} ----
    float m0 = mlLds[0][0][col], m1 = mlLds[1][0][col];
    float M = fmaxf(m0, m1);
    float s0 = EXP2(m0 - M), s1 = EXP2(m1 - M);
    float L = mlLds[0][1][col] * s0 + mlLds[1][1][col] * s1;
    float inv = 1.0f / L;
    size_t rowbase = (size_t)(b * T_ + qcol) * C_ + h * HD;
#pragma unroll
    for (int j = 0; j < 32; j++) {
      int R = w * 32 + j;               // merged reg index 0..63
      float merged = (oLds[0][R][lane] * s0 + oLds[1][R][lane] * s1) * inv;
      int db = R >> 4, r = R & 15;
      int d = (r & 3) + 8 * (r >> 2) + hioff;
      AO[rowbase + db * 32 + d] = f2b(merged);
    }
    __syncthreads();                    // protect LDS reuse in next phase
  }
}

extern "C" void kernel_launch(void* const* d_in, const int* in_sizes, int n_in,
                              void* d_out, int out_size, void* d_ws, size_t ws_size,
                              hipStream_t stream) {
  const float* x  = (const float*)d_in[0];
  // d_in[1] = mask (causal tril) — implicit in the kernel
  const float* wq = (const float*)d_in[2];
  const float* wk = (const float*)d_in[3];
  const float* wv = (const float*)d_in[4];
  const float* wo = (const float*)d_in[5];

  char* ws = (char*)d_ws;
  size_t off = 0;
  auto alloc = [&](size_t bytes) { char* p = ws + off; off += (bytes + 255) & ~255ull; return p; };
  ushort_t* Qb  = (ushort_t*)alloc((size_t)M_ * C_ * 2);
  ushort_t* Kb  = (ushort_t*)alloc((size_t)M_ * C_ * 2);
  ushort_t* Vb  = (ushort_t*)alloc((size_t)M_ * C_ * 2);
  ushort_t* Vtb = (ushort_t*)alloc((size_t)M_ * C_ * 2);
  ushort_t* xb  = (ushort_t*)alloc((size_t)M_ * C_ * 2);
  ushort_t* AO  = xb;  // alias: xb dead after QKV GEMM
  ushort_t* wqt = (ushort_t*)alloc((size_t)C_ * C_ * 2);
  ushort_t* wkt = (ushort_t*)alloc((size_t)C_ * C_ * 2);
  ushort_t* wvt = (ushort_t*)alloc((size_t)C_ * C_ * 2);
  ushort_t* wot = (ushort_t*)alloc((size_t)C_ * C_ * 2);
  float* cs = (float*)alloc((size_t)T_ * 64 * 4);
  float* sn = (float*)alloc((size_t)T_ * 64 * 4);

  // 1. x -> bf16
  cvt_f32_bf16<<<(M_ * C_ / 4 + 255) / 256, 256, 0, stream>>>(x, xb, M_ * C_ / 4);
  // 2. weights -> bf16 transposed (N,K)
  dim3 tg(C_ / 64, C_ / 64);
  transpose_to_bf16<1><<<tg, 256, 0, stream>>>(wq, wqt, C_, C_);
  transpose_to_bf16<1><<<tg, 256, 0, stream>>>(wk, wkt, C_, C_);
  transpose_to_bf16<1><<<tg, 256, 0, stream>>>(wv, wvt, C_, C_);
  transpose_to_bf16<1><<<tg, 256, 0, stream>>>(wo, wot, C_, C_);
  // 3. RoPE tables
  rope_table<<<T_ * 64 / 256, 256, 0, stream>>>(cs, sn);
  // 4. QKV projections (256x128 3-deep pipelined GEMM, 144 KiB dynamic LDS, 768 blocks = 3 rounds)
  gemm_bt3<0><<<dim3(C_ / 128, M_ / 256, 3), 512, 147456, stream>>>(
      xb, wqt, wkt, wvt, Qb, Kb, Vb, C_, C_);
  // 5. RoPE on Q, K
  rope_apply<<<M_ * C_ / 8 / 256, 256, 0, stream>>>(Qb, Kb, cs, sn);
  // 6. V -> Vt per batch (2048x2048 transpose each)
  for (int b = 0; b < B_; b++)
    transpose_to_bf16<0><<<dim3(T_ / 64, T_ / 64), 256, 0, stream>>>(
        Vb + (size_t)b * T_ * C_, Vtb + (size_t)b * T_ * C_, T_, C_);
  // 7. flash attention v4 (2-wave KV split + exact merge)
  flash_attn4<<<dim3(B_ * NH * 32), 128, 0, stream>>>(Qb, Kb, Vtb, AO);
  // 8. output projection -> fp32 d_out (256 blocks = 1 full round)
  gemm_bt3<1><<<dim3(C_ / 128, M_ / 256, 1), 512, 147456, stream>>>(
      AO, wot, wot, wot, d_out, d_out, d_out, C_, C_);
  (void)in_sizes; (void)n_in; (void)out_size; (void)ws_size;
}